// Round 9
// baseline (1140.903 us; speedup 1.0000x reference)
//
#include <hip/hip_runtime.h>
#include <math.h>

#define BB 8
#define CC 256
#define NN 2048

static const size_t NC  = (size_t)NN * CC;
static const size_t CN  = (size_t)CC * NN;

typedef unsigned short u16;
typedef __attribute__((ext_vector_type(8))) short short8;   // 8 bf16 (one MFMA frag)
typedef __attribute__((ext_vector_type(4))) float f32x4;    // MFMA acc

__device__ __forceinline__ float bf2f(u16 v) {
    union { unsigned int u; float f; } t; t.u = ((unsigned int)v) << 16; return t.f;
}
__device__ __forceinline__ u16 f2bf(float f) {
    union { float f; unsigned int u; } t; t.f = f;
    return (u16)((t.u + 0x7fffu + ((t.u >> 16) & 1u)) >> 16);
}
__device__ __forceinline__ float sigf(float x) { return 1.0f / (1.0f + expf(-x)); }

// ---------------------------------------------------------------------------
// 16x32-tiled layout: logical (r,c) of an [R][C] slab; tpr = C/32 tiles/row.
// Tile = 16 rows x 32 cols = 1KB contiguous; one MFMA fragment = one tile.
// ---------------------------------------------------------------------------
__device__ __forceinline__ size_t til(int r, int c, int tpr) {
    return (((size_t)((r >> 4) * tpr + (c >> 5))) << 9)
         + (size_t)((r & 15) << 5) + (size_t)(c & 31);
}

// async global->LDS stage of one 1KB tile, granule-transposed (round-8 proven)
__device__ __forceinline__ void stage_tile(const u16* gtile, u16* ldst, int lane) {
    const u16* src = gtile + (lane & 15) * 32 + (lane >> 4) * 8;
    __builtin_amdgcn_global_load_lds(
        (const __attribute__((address_space(1))) void*)src,
        (__attribute__((address_space(3))) void*)ldst, 16, 0, 0);
}
#define WAITV(n) asm volatile("s_waitcnt vmcnt(" #n ")" ::: "memory")

// ---------------------------------------------------------------------------
// weights fp32 [mat][256][256] -> bf16 tiled (c16,k32)
// ---------------------------------------------------------------------------
__global__ __launch_bounds__(256) void cast_w(const float* __restrict__ in,
                                              u16* __restrict__ outp)
{
    const int mat = blockIdx.y;
    const int idx = blockIdx.x * 256 + threadIdx.x;    // 0..16383
    const int c = idx >> 6, k = (idx & 63) << 2;
    const float4 v = *(const float4*)&in[(size_t)mat * (CC * CC) + (size_t)c * CC + k];
    ushort4 p;
    p.x = f2bf(v.x); p.y = f2bf(v.y); p.z = f2bf(v.z); p.w = f2bf(v.w);
    *(ushort4*)&outp[(size_t)mat * (CC * CC) + til(c, k, CC / 32)] = p;
}

// ---------------------------------------------------------------------------
// transpose-cast x: Xt[z] tiled(n16,c32) = bf16(x[z][c][n]); z = b*3+slice
// ---------------------------------------------------------------------------
__global__ __launch_bounds__(256) void tcast_x(const float* __restrict__ in,
                                               u16* __restrict__ out)
{
    const int z = blockIdx.z;
    const float* I = in + (size_t)z * CN;
    u16* O = out + (size_t)z * NC;
    const int c0 = blockIdx.y * 64, n0 = blockIdx.x * 64;
    const int tx = threadIdx.x & 15, ty = threadIdx.x >> 4;

    __shared__ float t[64][68];

    #pragma unroll
    for (int cc = 0; cc < 64; cc += 16) {
        const int c = ty + cc;
        *(float4*)&t[c][tx * 4] = *(const float4*)&I[(size_t)(c0 + c) * NN + n0 + tx * 4];
    }
    __syncthreads();
    #pragma unroll
    for (int nn2 = 0; nn2 < 64; nn2 += 16) {
        const int n = n0 + ty + nn2;
        const int c = c0 + tx * 4;
        ushort4 p;
        p.x = f2bf(t[tx * 4 + 0][ty + nn2]);
        p.y = f2bf(t[tx * 4 + 1][ty + nn2]);
        p.z = f2bf(t[tx * 4 + 2][ty + nn2]);
        p.w = f2bf(t[tx * 4 + 3][ty + nn2]);
        *(ushort4*)&O[til(n, c, 8)] = p;
    }
}

// ---------------------------------------------------------------------------
// Q/K/V conv via MFMA, table-driven, all operands tiled. (round-5 proven)
// ---------------------------------------------------------------------------
struct QkvP {
    const u16* w[12]; const u16* x[12]; u16* out[12];
    const float* bias[12]; int isv[12];
};

__global__ __launch_bounds__(256) void conv_qkv(QkvP P)
{
    const int z = blockIdx.z, job = z >> 3, b = z & 7;
    const int isv = P.isv[job];
    const u16* Wp = P.w[job];
    const u16* Xp = P.x[job] + (size_t)b * (3 * NC);
    const int n0 = blockIdx.x * 128, c0 = blockIdx.y * 128;
    const int lane = threadIdx.x & 63, wave = threadIdx.x >> 6;
    const int l15 = lane & 15, lg = lane >> 4;
    const int rA = (wave >> 1) * 64, rB = (wave & 1) * 64;

    const u16* Ab = isv ? Xp : Wp;
    const u16* Bb = isv ? Wp : Xp;
    const int Ar0 = (isv ? n0 : c0) + rA;
    const int Br0 = (isv ? c0 : n0) + rB;

    const u16* ap[4]; const u16* bp[4];
    #pragma unroll
    for (int i = 0; i < 4; i++) {
        ap[i] = Ab + til(Ar0 + i * 16 + l15, lg * 8, 8);
        bp[i] = Bb + til(Br0 + i * 16 + l15, lg * 8, 8);
    }

    f32x4 acc[4][4] = {};
    #pragma unroll 2
    for (int kc = 0; kc < 8; kc++) {
        short8 av[4], bv[4];
        #pragma unroll
        for (int i = 0; i < 4; i++) av[i] = *(const short8*)(ap[i] + kc * 512);
        #pragma unroll
        for (int i = 0; i < 4; i++) bv[i] = *(const short8*)(bp[i] + kc * 512);
        #pragma unroll
        for (int i = 0; i < 4; i++)
            #pragma unroll
            for (int j = 0; j < 4; j++)
                acc[i][j] = __builtin_amdgcn_mfma_f32_16x16x32_bf16(av[i], bv[j], acc[i][j], 0, 0, 0);
    }

    if (!isv) {
        u16* Ot = P.out[job] + (size_t)b * NC;
        #pragma unroll
        for (int i = 0; i < 4; i++) {
            const int c = c0 + rA + i * 16 + lg * 4;    // reg-packed dim
            #pragma unroll
            for (int j = 0; j < 4; j++) {
                const int n = n0 + rB + j * 16 + l15;
                ushort4 p;
                p.x = f2bf(acc[i][j][0]); p.y = f2bf(acc[i][j][1]);
                p.z = f2bf(acc[i][j][2]); p.w = f2bf(acc[i][j][3]);
                *(ushort4*)&Ot[til(n, c, 8)] = p;
            }
        }
    } else {
        u16* Ov = P.out[job] + (size_t)b * CN;
        const float* bias = P.bias[job];
        #pragma unroll
        for (int j = 0; j < 4; j++) {
            const int c = c0 + rB + j * 16 + l15;
            const float bi = bias[c];
            #pragma unroll
            for (int i = 0; i < 4; i++) {
                const int n = n0 + rA + i * 16 + lg * 4;  // reg-packed dim
                ushort4 p;
                p.x = f2bf(acc[i][j][0] + bi); p.y = f2bf(acc[i][j][1] + bi);
                p.z = f2bf(acc[i][j][2] + bi); p.w = f2bf(acc[i][j][3] + bi);
                *(ushort4*)&Ov[til(c, n, 64)] = p;
            }
        }
    }
}

// ---------------------------------------------------------------------------
// T-stage conv, bf16 in/out (round-7 proven)
// ---------------------------------------------------------------------------
__global__ __launch_bounds__(256) void conv_t2(
    const u16* __restrict__ W, const u16* __restrict__ Dt,
    const float* __restrict__ bias, const u16* __restrict__ Xts,
    u16* __restrict__ O)
{
    const int bid = blockIdx.x;
    const int b = bid & 7;
    const int rest = bid >> 3;           // 0..31
    const int cy = rest & 1, nx = rest >> 1;
    const int n0 = nx * 128, c0 = cy * 128;
    const int lane = threadIdx.x & 63, wave = threadIdx.x >> 6;
    const int l15 = lane & 15, lg = lane >> 4;
    const int wc = (wave >> 1) * 64, wn = (wave & 1) * 64;

    const u16* Xp = Dt + (size_t)b * NC;
    const u16* ap[4]; const u16* bp[4];
    #pragma unroll
    for (int i = 0; i < 4; i++) {
        ap[i] = W  + til(c0 + wc + i * 16 + l15, lg * 8, 8);
        bp[i] = Xp + til(n0 + wn + i * 16 + l15, lg * 8, 8);
    }

    f32x4 acc[4][4] = {};
    #pragma unroll 2
    for (int kc = 0; kc < 8; kc++) {
        short8 av[4], bv[4];
        #pragma unroll
        for (int i = 0; i < 4; i++) av[i] = *(const short8*)(ap[i] + kc * 512);
        #pragma unroll
        for (int i = 0; i < 4; i++) bv[i] = *(const short8*)(bp[i] + kc * 512);
        #pragma unroll
        for (int i = 0; i < 4; i++)
            #pragma unroll
            for (int j = 0; j < 4; j++)
                acc[i][j] = __builtin_amdgcn_mfma_f32_16x16x32_bf16(av[i], bv[j], acc[i][j], 0, 0, 0);
    }

    const u16* Xtb = Xts + (size_t)b * (3 * NC);
    u16* Ob = O + (size_t)b * CN;
    #pragma unroll
    for (int i = 0; i < 4; i++) {
        const int cb = c0 + wc + i * 16 + lg * 4;
        #pragma unroll
        for (int j = 0; j < 4; j++) {
            const int n = n0 + wn + j * 16 + l15;
            const ushort4 xv = *(const ushort4*)&Xtb[til(n, cb, 8)];
            const u16 xa[4] = { xv.x, xv.y, xv.z, xv.w };
            #pragma unroll
            for (int r = 0; r < 4; r++) {
                const int c = cb + r;
                const float v = bf2f(xa[r]) + fmaxf(acc[i][j][r] + bias[c], 0.0f);
                Ob[til(c, n, 64)] = f2bf(v);
            }
        }
    }
}

// ---------------------------------------------------------------------------
// attention pass 1: identical to round-8 attn_mfma6 but NO S store.
// Outputs: rowstats RS[b][n][2] = {rowmax, 1/rowsum}, column partials CP.
// ---------------------------------------------------------------------------
__global__ __launch_bounds__(1024) void attn_pass1(
    const u16* __restrict__ Q, const u16* __restrict__ K,
    float* __restrict__ RSg, float* __restrict__ CPb)
{
    const int bid = blockIdx.x;
    const int b = bid & 7;
    const int nblk = bid >> 3;           // 0..63
    const int n0 = nblk * 32;
    const int tid = threadIdx.x, lane = tid & 63, wave = tid >> 6;
    const int l15 = lane & 15, lg = lane >> 4;

    const u16* Qt = Q + (size_t)b * NC;
    const u16* Kt = K + (size_t)b * NC;

    __shared__ u16 KL[16 * 8 * 512];     // 16 waves x 8 slots x 1KB = 128 KiB
    __shared__ u16 QL[16 * 512];         // 16 Q tiles
    __shared__ float red[16][32];
    __shared__ float rowstat[32];

    stage_tile(Qt + ((size_t)((n0 >> 4) + (wave >> 3)) * 8 + (wave & 7)) * 512,
               &QL[wave * 512], lane);
    u16* kw = &KL[wave * 4096];
    #pragma unroll
    for (int p = 0; p < 6; p++)
        stage_tile(Kt + ((size_t)(wave * 8 + (p & 7)) * 8 + (p >> 3)) * 512,
                   &kw[p * 512], lane);
    __syncthreads();

    f32x4 acc[2][8];
    #pragma unroll
    for (int g = 0; g < 2; g++)
        #pragma unroll
        for (int t = 0; t < 8; t++) acc[g][t] = (f32x4){0.f, 0.f, 0.f, 0.f};

    const int roff = lg * 128 + l15 * 8;

    #pragma unroll
    for (int kc = 0; kc < 8; kc++) {
        const short8 a0 = *(const short8*)&QL[kc * 512 + roff];
        const short8 a1 = *(const short8*)&QL[(8 + kc) * 512 + roff];
        #pragma unroll
        for (int t = 0; t < 8; t++) {
            const int i = kc * 8 + t;
            if (i < 58) { WAITV(5); } else if (i == 58) { WAITV(0); }
            const short8 bf = *(const short8*)&kw[(i & 7) * 512 + roff];
            if (i + 6 < 64) {
                const int j = i + 6;
                stage_tile(Kt + ((size_t)(wave * 8 + (j & 7)) * 8 + (j >> 3)) * 512,
                           &kw[(j & 7) * 512], lane);
            }
            __builtin_amdgcn_s_setprio(1);
            acc[0][t] = __builtin_amdgcn_mfma_f32_16x16x32_bf16(a0, bf, acc[0][t], 0, 0, 0);
            acc[1][t] = __builtin_amdgcn_mfma_f32_16x16x32_bf16(a1, bf, acc[1][t], 0, 0, 0);
            __builtin_amdgcn_s_setprio(0);
        }
    }

    // ---- row max ----
    float pm[2][4];
    #pragma unroll
    for (int g = 0; g < 2; g++)
        #pragma unroll
        for (int r = 0; r < 4; r++) {
            float m = acc[g][0][r];
            #pragma unroll
            for (int t = 1; t < 8; t++) m = fmaxf(m, acc[g][t][r]);
            #pragma unroll
            for (int o = 1; o <= 8; o <<= 1) m = fmaxf(m, __shfl_xor(m, o));
            pm[g][r] = m;
        }
    if (l15 == 0) {
        #pragma unroll
        for (int g = 0; g < 2; g++)
            #pragma unroll
            for (int r = 0; r < 4; r++) red[wave][g * 16 + lg * 4 + r] = pm[g][r];
    }
    __syncthreads();
    if (tid < 32) {
        float m = red[0][tid];
        #pragma unroll
        for (int w = 1; w < 16; w++) m = fmaxf(m, red[w][tid]);
        rowstat[tid] = m;
        RSg[((size_t)b * NN + n0 + tid) * 2] = m;          // rowmax
    }
    __syncthreads();

    float rm[2][4], ps[2][4];
    #pragma unroll
    for (int g = 0; g < 2; g++)
        #pragma unroll
        for (int r = 0; r < 4; r++) { rm[g][r] = rowstat[g * 16 + lg * 4 + r]; ps[g][r] = 0.f; }
    __syncthreads();

    // ---- exp in place + row-sum ----
    #pragma unroll
    for (int g = 0; g < 2; g++)
        #pragma unroll
        for (int t = 0; t < 8; t++)
            #pragma unroll
            for (int r = 0; r < 4; r++) {
                const float e = __expf(acc[g][t][r] - rm[g][r]);
                acc[g][t][r] = e; ps[g][r] += e;
            }
    #pragma unroll
    for (int g = 0; g < 2; g++)
        #pragma unroll
        for (int r = 0; r < 4; r++)
            #pragma unroll
            for (int o = 1; o <= 8; o <<= 1) ps[g][r] += __shfl_xor(ps[g][r], o);
    if (l15 == 0) {
        #pragma unroll
        for (int g = 0; g < 2; g++)
            #pragma unroll
            for (int r = 0; r < 4; r++) red[wave][g * 16 + lg * 4 + r] = ps[g][r];
    }
    __syncthreads();
    if (tid < 32) {
        float s = red[0][tid];
        #pragma unroll
        for (int w = 1; w < 16; w++) s += red[w][tid];
        const float inv = 1.0f / s;
        rowstat[tid] = inv;
        RSg[((size_t)b * NN + n0 + tid) * 2 + 1] = inv;    // 1/rowsum
    }
    __syncthreads();

    float rv[2][4];
    #pragma unroll
    for (int g = 0; g < 2; g++)
        #pragma unroll
        for (int r = 0; r < 4; r++) rv[g][r] = rowstat[g * 16 + lg * 4 + r];

    // ---- column partials only (no S store) ----
    float* cpb = CPb + ((size_t)b * 64 + nblk) * NN;
    #pragma unroll
    for (int t = 0; t < 8; t++) {
        const int m = wave * 128 + t * 16 + l15;
        float cs = 0.0f;
        #pragma unroll
        for (int g = 0; g < 2; g++)
            cs += acc[g][t][0] * rv[g][0] + acc[g][t][1] * rv[g][1]
                + acc[g][t][2] * rv[g][2] + acc[g][t][3] * rv[g][3];
        cs += __shfl_xor(cs, 16);
        cs += __shfl_xor(cs, 32);
        if (lane < 16) cpb[m] = cs;
    }
}

// ---------------------------------------------------------------------------
// colsum[b][m] = sum_{g<64} cspart[b][g][m]   (round-5 proven)
// ---------------------------------------------------------------------------
__global__ __launch_bounds__(256) void csum_kernel(const float* __restrict__ cp,
                                                   float* __restrict__ cs)
{
    const int b  = blockIdx.y;
    const int ml = threadIdx.x & 63;
    const int m  = blockIdx.x * 64 + ml;
    const int g0 = threadIdx.x >> 6;
    float s = 0.0f;
    for (int g = g0; g < 64; g += 4)
        s += cp[((size_t)b * 64 + g) * NN + m];
    __shared__ float red[4][64];
    red[g0][ml] = s;
    __syncthreads();
    if (threadIdx.x < 64) {
        cs[(size_t)b * NN + blockIdx.x * 64 + threadIdx.x] =
            red[0][threadIdx.x] + red[1][threadIdx.x] +
            red[2][threadIdx.x] + red[3][threadIdx.x];
    }
}

// ---------------------------------------------------------------------------
// pass 2: fused QK^T-recompute + softmax-apply + PV + Dt. No S in HBM.
// 256 blocks (8 b x 32 m-tiles, XCD-pinned), 512 thr (8 waves).
// Per chunk of 32 n: wave (wn2,wm4) computes one 16n x 16m logit tile
// (bit-identical to pass 1), applies exp(l-rm)*rinv, writes p-tile to LDS;
// barrier; wave (wc4,wm2) does PV MFMAs with V from L2. Epilogue = pv's.
// ---------------------------------------------------------------------------
__global__ __launch_bounds__(512) void pv_fuse(
    const u16* __restrict__ Q, const u16* __restrict__ K,
    const u16* __restrict__ V, const float* __restrict__ RSg,
    const float* __restrict__ CSb, const u16* __restrict__ Xts,
    u16* __restrict__ DTo)
{
    const int bid = blockIdx.x;
    const int b = bid & 7;
    const int mx = bid >> 3;             // 0..31
    const int m0 = mx * 64;
    const int tid = threadIdx.x, lane = tid & 63, wave = tid >> 6;
    const int l15 = lane & 15, lg = lane >> 4, rb = lg * 4;
    const int wn2 = wave >> 2, wm4 = wave & 3;   // QK role
    const int wc4 = wave >> 1, wm2 = wave & 1;   // PV role

    const u16* Qt = Q + (size_t)b * NC;
    const u16* Kt = K + (size_t)b * NC;
    const u16* Vm = V + (size_t)b * CN;

    __shared__ u16 KT[32 * 512];         // 32 K tiles, granule-transposed (32KB)
    __shared__ u16 SB[64 * 40];          // p-tile [m][n32], padded rows (5KB)
    __shared__ float2 rsl[NN];           // rowstats (16KB)
    __shared__ float csl[64];

    // stage K m-tile (4 mt x 8 kc) transposed; wave stages 4 tiles
    #pragma unroll
    for (int j = 0; j < 4; j++) {
        const int t = wave * 4 + j;      // mt = t>>3, kc = t&7
        stage_tile(Kt + ((size_t)((mx * 4 + (t >> 3)) * 8) + (t & 7)) * 512,
                   &KT[t * 512], lane);
    }
    for (int k = tid; k < NN; k += 512)
        rsl[k] = ((const float2*)RSg)[(size_t)b * NN + k];
    if (tid < 64) csl[tid] = 1.0f / (1e-7f + CSb[(size_t)b * NN + m0 + tid]);
    __syncthreads();   // drains vmcnt for KT stages too

    const int roff = lg * 128 + l15 * 8;
    const int sbw = (wm4 * 16 + l15) * 40 + wn2 * 16 + rb;     // SB write (u16)
    const int sbr = (wm2 * 32 + l15) * 40 + lg * 8;            // SB read base

    f32x4 acc[4][2] = {};

    for (int ch = 0; ch < 64; ch++) {
        // ---- QK: one 16n x 16m logit tile ----
        const int n0c = ch * 32 + wn2 * 16;
        const u16* qb = Qt + ((size_t)(n0c >> 4) * 8) * 512 + l15 * 32 + lg * 8;
        f32x4 qk = (f32x4){0.f, 0.f, 0.f, 0.f};
        #pragma unroll
        for (int kc = 0; kc < 8; kc++) {
            const short8 a  = *(const short8*)(qb + kc * 512);
            const short8 bf = *(const short8*)&KT[(wm4 * 8 + kc) * 512 + roff];
            qk = __builtin_amdgcn_mfma_f32_16x16x32_bf16(a, bf, qk, 0, 0, 0);
        }
        ushort4 pk;
        {
            const float2 s0 = rsl[n0c + rb + 0];
            const float2 s1 = rsl[n0c + rb + 1];
            const float2 s2 = rsl[n0c + rb + 2];
            const float2 s3 = rsl[n0c + rb + 3];
            pk.x = f2bf(__expf(qk[0] - s0.x) * s0.y);
            pk.y = f2bf(__expf(qk[1] - s1.x) * s1.y);
            pk.z = f2bf(__expf(qk[2] - s2.x) * s2.y);
            pk.w = f2bf(__expf(qk[3] - s3.x) * s3.y);
        }
        *(ushort4*)&SB[sbw] = pk;
        __syncthreads();

        // ---- PV: acc += V(64c x 32n) * p(32n x 32m-half) ----
        short8 vf[4], sf[2];
        #pragma unroll
        for (int ai = 0; ai < 4; ai++)
            vf[ai] = *(const short8*)(Vm + til(wc4 * 64 + ai * 16 + l15,
                                               ch * 32 + lg * 8, 64));
        #pragma unroll
        for (int bj = 0; bj < 2; bj++)
            sf[bj] = *(const short8*)&SB[sbr + bj * 16 * 40];
        #pragma unroll
        for (int ai = 0; ai < 4; ai++)
            #pragma unroll
            for (int bj = 0; bj < 2; bj++)
                acc[ai][bj] = __builtin_amdgcn_mfma_f32_16x16x32_bf16(
                                  vf[ai], sf[bj], acc[ai][bj], 0, 0, 0);
        __syncthreads();
    }

    // ---- epilogue: Dt tiled(m16,c32) = bf16(Xt - acc*colinv) ----
    const u16* Xtb = Xts + (size_t)b * (3 * NC);
    u16* Dtb = DTo + (size_t)b * NC;
    #pragma unroll
    for (int bj = 0; bj < 2; bj++) {
        const int mloc = wm2 * 32 + bj * 16 + l15;
        const int m = m0 + mloc;
        const float inv = csl[mloc];
        #pragma unroll
        for (int ai = 0; ai < 4; ai++) {
            const int c = wc4 * 64 + ai * 16 + rb;   // reg-packed dim
            const size_t ad = til(m, c, 8);
            const ushort4 xv = *(const ushort4*)&Xtb[ad];
            ushort4 pk;
            pk.x = f2bf(bf2f(xv.x) - acc[ai][bj][0] * inv);
            pk.y = f2bf(bf2f(xv.y) - acc[ai][bj][1] * inv);
            pk.z = f2bf(bf2f(xv.z) - acc[ai][bj][2] * inv);
            pk.w = f2bf(bf2f(xv.w) - acc[ai][bj][3] * inv);
            *(ushort4*)&Dtb[ad] = pk;
        }
    }
}

// ---------------------------------------------------------------------------
// elementwise combines on bf16 tiled slabs (round-7 proven)
// ---------------------------------------------------------------------------
__global__ __launch_bounds__(256) void ew_update_t(u16* __restrict__ A,
                                                   const u16* __restrict__ Bv)
{
    const size_t e = ((size_t)blockIdx.x * 256 + threadIdx.x) * 8;
    short8 a = *(const short8*)&A[e];
    const short8 b = *(const short8*)&Bv[e];
    #pragma unroll
    for (int j = 0; j < 8; j++) {
        const float f = tanhf(bf2f((u16)a[j]) * sigf(bf2f((u16)b[j])));
        a[j] = (short)f2bf(f);
    }
    *(short8*)&A[e] = a;
}

__global__ __launch_bounds__(256) void ew_final_t(
    const u16* __restrict__ TU, const u16* __restrict__ SU,
    const u16* __restrict__ G, const float* __restrict__ x,
    float* __restrict__ OUT)
{
    const size_t e = ((size_t)blockIdx.x * 256 + threadIdx.x) * 8;
    const int b = (int)(e / CN);
    const size_t r = e - (size_t)b * CN;
    const int tile = (int)(r >> 9), win = (int)(r & 511);
    const int row = win >> 5, col = win & 31;
    const int c = (tile >> 6) * 16 + row;      // tiled(c16,n32), tpr=64
    const int n = (tile & 63) * 32 + col;

    const size_t lin = ((size_t)b * 3 + 1) * CN + (size_t)c * NN + n;  // mid slice
    const float4 m0 = *(const float4*)&x[lin];
    const float4 m1 = *(const float4*)&x[lin + 4];
    const float mid[8] = { m0.x, m0.y, m0.z, m0.w, m1.x, m1.y, m1.z, m1.w };

    const short8 tu = *(const short8*)&TU[e];
    const short8 su = *(const short8*)&SU[e];
    const short8 g  = *(const short8*)&G[e];

    float o[8];
    #pragma unroll
    for (int j = 0; j < 8; j++) {
        const float gg = bf2f((u16)g[j]);
        o[j] = mid[j] + sigf((bf2f((u16)tu[j]) + bf2f((u16)su[j])) * sigf(gg)) * tanhf(gg);
    }
    float* op = OUT + (size_t)b * CN + (size_t)c * NN + n;
    *(float4*)op       = (float4){o[0], o[1], o[2], o[3]};
    *(float4*)(op + 4) = (float4){o[4], o[5], o[6], o[7]};
}

// ---------------------------------------------------------------------------
extern "C" void kernel_launch(void* const* d_in, const int* in_sizes, int n_in,
                              void* d_out, int out_size, void* d_ws, size_t ws_size,
                              hipStream_t stream)
{
    const float* x   = (const float*)d_in[0];
    const float* Wqk = (const float*)d_in[1];
    const float* Vw  = (const float*)d_in[2];
    const float* VbF = (const float*)d_in[3];
    const float* Tw  = (const float*)d_in[4];
    const float* TbF = (const float*)d_in[5];
    float* out = (float*)d_out;

    // module meta: x-side slice (K,V) and y-side slice (Q). time=0 mid=1 space=2
    const int mxs[5] = {0, 2, 0, 2, 1};
    const int mys[5] = {0, 2, 2, 0, 1};
    const int qjob[5] = {0, 1, 5, 6, 4};
    const int q_wi[7] = {0, 1, 2, 3, 4, 2, 3};
    const int q_xi[7] = {0, 2, 0, 2, 1, 2, 0};

    const size_t WSZ     = (size_t)CC * CC;
    const size_t QK_SLAB = (size_t)BB * NC;              // elems (bf16)
    const size_t CP_SLAB = (size_t)BB * 64 * NN;         // elems (f32)
    const size_t CS_SLAB = (size_t)BB * NN;              // elems (f32)
    const size_t RS_SLAB = (size_t)BB * NN * 2;          // elems (f32)
    const size_t O_SLAB  = (size_t)BB * CN;              // elems (bf16)

    const size_t base_b = 15 * WSZ * 2 + (size_t)BB * 3 * NC * 2;
    const size_t modtl  = CP_SLAB * 4 + CS_SLAB * 4 + RS_SLAB * 4 + QK_SLAB * 2;
    const size_t margin = 2u << 20;
    const size_t need_1 = base_b + 12 * QK_SLAB * 2 + modtl + 3 * O_SLAB * 2 + margin;
    const size_t need_2 = base_b +  3 * QK_SLAB * 2 + modtl + 3 * O_SLAB * 2 + margin;

    const int tier2 = (ws_size >= need_1) ? 0 : 1;
    if (tier2 && ws_size < need_2) return;   // can't run: leave poison

    const int nQK = tier2 ? 2 : 7;
    const int nV  = tier2 ? 1 : 5;

    char* ws = (char*)d_ws;
    size_t off = 0;
    auto alloc = [&](size_t bytes) -> char* {
        char* p = ws + off; off += (bytes + 255) & ~255ULL; return p;
    };

    u16*   W16 = (u16*)  alloc(15 * WSZ * 2);
    u16*   Xt  = (u16*)  alloc((size_t)BB * 3 * NC * 2);
    u16*   QK  = (u16*)  alloc((size_t)nQK * QK_SLAB * 2);
    u16*   VB  = (u16*)  alloc((size_t)nV * QK_SLAB * 2);
    float* CP  = (float*)alloc(CP_SLAB * 4);
    float* CS  = (float*)alloc(CS_SLAB * 4);
    float* RS  = (float*)alloc(RS_SLAB * 4);
    u16*   DT  = (u16*)  alloc(QK_SLAB * 2);
    u16*   OB  = (u16*)  alloc(3 * O_SLAB * 2);

    cast_w<<<dim3(64, 5), 256, 0, stream>>>(Wqk, W16);
    cast_w<<<dim3(64, 5), 256, 0, stream>>>(Vw,  W16 + 5 * WSZ);
    cast_w<<<dim3(64, 5), 256, 0, stream>>>(Tw,  W16 + 10 * WSZ);
    tcast_x<<<dim3(NN / 64, CC / 64, BB * 3), 256, 0, stream>>>(x, Xt);

    if (!tier2) {
        QkvP qp{};
        for (int j = 0; j < 7; j++) {
            qp.w[j] = W16 + (size_t)q_wi[j] * WSZ;
            qp.x[j] = Xt + (size_t)q_xi[j] * NC;
            qp.out[j] = QK + (size_t)j * QK_SLAB;
            qp.isv[j] = 0; qp.bias[j] = nullptr;
        }
        for (int i = 0; i < 5; i++) {
            const int j = 7 + i;
            qp.w[j] = W16 + (size_t)(5 + i) * WSZ;
            qp.x[j] = Xt + (size_t)mxs[i] * NC;
            qp.out[j] = VB + (size_t)i * QK_SLAB;
            qp.isv[j] = 1; qp.bias[j] = VbF + (size_t)i * CC;
        }
        conv_qkv<<<dim3(NN / 128, CC / 128, 96), 256, 0, stream>>>(qp);
    }

    auto run_mod = [&](int i, u16* O) {
        const u16* Qp; const u16* Kp; const u16* Vp;
        if (!tier2) {
            Qp = QK + (size_t)qjob[i] * QK_SLAB;
            Kp = QK + (size_t)i * QK_SLAB;
            Vp = VB + (size_t)i * QK_SLAB;
        } else {
            QkvP qp{}; int nj = 0;
            qp.w[nj] = W16 + (size_t)i * WSZ; qp.x[nj] = Xt + (size_t)mxs[i] * NC;
            qp.out[nj] = QK; qp.isv[nj] = 0; nj++;
            Qp = QK; Kp = QK;
            if (mys[i] != mxs[i]) {
                qp.w[nj] = W16 + (size_t)i * WSZ; qp.x[nj] = Xt + (size_t)mys[i] * NC;
                qp.out[nj] = QK + QK_SLAB; qp.isv[nj] = 0; nj++;
                Qp = QK + QK_SLAB;
            }
            qp.w[nj] = W16 + (size_t)(5 + i) * WSZ; qp.x[nj] = Xt + (size_t)mxs[i] * NC;
            qp.out[nj] = VB; qp.isv[nj] = 1; qp.bias[nj] = VbF + (size_t)i * CC; nj++;
            conv_qkv<<<dim3(NN / 128, CC / 128, 8 * nj), 256, 0, stream>>>(qp);
            Vp = VB;
        }
        attn_pass1<<<512, 1024, 0, stream>>>(Qp, Kp, RS, CP);
        csum_kernel<<<dim3(NN / 64, BB), 256, 0, stream>>>(CP, CS);
        pv_fuse<<<256, 512, 0, stream>>>(Qp, Kp, Vp, RS, CS,
                                         Xt + (size_t)mxs[i] * NC, DT);
        conv_t2<<<256, 256, 0, stream>>>(W16 + (size_t)(10 + i) * WSZ, DT,
                                         TbF + (size_t)i * CC,
                                         Xt + (size_t)mxs[i] * NC, O);
    };

    u16* OB0 = OB;
    u16* OB1 = OB + O_SLAB;
    u16* OB2 = OB + 2 * O_SLAB;
    const int ewg = (int)(((size_t)BB * CN) / (256 * 8));   // 2048 blocks

    run_mod(0, OB0);                                         // time_att
    run_mod(2, OB1);                                         // time_cor
    ew_update_t<<<ewg, 256, 0, stream>>>(OB0, OB1);          // OB0 = time_update
    run_mod(1, OB1);                                         // space_att
    run_mod(3, OB2);                                         // space_cor
    ew_update_t<<<ewg, 256, 0, stream>>>(OB1, OB2);          // OB1 = space_update
    run_mod(4, OB2);                                         // global_feat
    ew_final_t<<<ewg, 256, 0, stream>>>(OB0, OB1, OB2, x, out);
}

// Round 10
// 642.598 us; speedup vs baseline: 1.7755x; 1.7755x over previous
//
#include <hip/hip_runtime.h>
#include <math.h>

#define BB 8
#define CC 256
#define NN 2048

static const size_t NC  = (size_t)NN * CC;
static const size_t CN  = (size_t)CC * NN;

typedef unsigned short u16;
typedef __attribute__((ext_vector_type(8))) short short8;   // 8 bf16 (one MFMA frag)
typedef __attribute__((ext_vector_type(4))) float f32x4;    // MFMA acc

__device__ __forceinline__ float bf2f(u16 v) {
    union { unsigned int u; float f; } t; t.u = ((unsigned int)v) << 16; return t.f;
}
__device__ __forceinline__ u16 f2bf(float f) {
    union { float f; unsigned int u; } t; t.f = f;
    return (u16)((t.u + 0x7fffu + ((t.u >> 16) & 1u)) >> 16);
}
__device__ __forceinline__ float sigf(float x) { return 1.0f / (1.0f + expf(-x)); }

// ---------------------------------------------------------------------------
// 16x32-tiled layout: logical (r,c) of an [R][C] slab; tpr = C/32 tiles/row.
// Tile = 16 rows x 32 cols = 1KB contiguous; one MFMA fragment = one tile.
// ---------------------------------------------------------------------------
__device__ __forceinline__ size_t til(int r, int c, int tpr) {
    return (((size_t)((r >> 4) * tpr + (c >> 5))) << 9)
         + (size_t)((r & 15) << 5) + (size_t)(c & 31);
}

// async global->LDS stage of one 1KB tile, granule-transposed (round-8 proven)
__device__ __forceinline__ void stage_tile(const u16* gtile, u16* ldst, int lane) {
    const u16* src = gtile + (lane & 15) * 32 + (lane >> 4) * 8;
    __builtin_amdgcn_global_load_lds(
        (const __attribute__((address_space(1))) void*)src,
        (__attribute__((address_space(3))) void*)ldst, 16, 0, 0);
}
#define WAITV(n) asm volatile("s_waitcnt vmcnt(" #n ")" ::: "memory")

// ---------------------------------------------------------------------------
// weights fp32 [mat][256][256] -> bf16 tiled (c16,k32)
// ---------------------------------------------------------------------------
__global__ __launch_bounds__(256) void cast_w(const float* __restrict__ in,
                                              u16* __restrict__ outp)
{
    const int mat = blockIdx.y;
    const int idx = blockIdx.x * 256 + threadIdx.x;    // 0..16383
    const int c = idx >> 6, k = (idx & 63) << 2;
    const float4 v = *(const float4*)&in[(size_t)mat * (CC * CC) + (size_t)c * CC + k];
    ushort4 p;
    p.x = f2bf(v.x); p.y = f2bf(v.y); p.z = f2bf(v.z); p.w = f2bf(v.w);
    *(ushort4*)&outp[(size_t)mat * (CC * CC) + til(c, k, CC / 32)] = p;
}

// ---------------------------------------------------------------------------
// transpose-cast x: Xt[z] tiled(n16,c32) = bf16(x[z][c][n]); z = b*3+slice
// ---------------------------------------------------------------------------
__global__ __launch_bounds__(256) void tcast_x(const float* __restrict__ in,
                                               u16* __restrict__ out)
{
    const int z = blockIdx.z;
    const float* I = in + (size_t)z * CN;
    u16* O = out + (size_t)z * NC;
    const int c0 = blockIdx.y * 64, n0 = blockIdx.x * 64;
    const int tx = threadIdx.x & 15, ty = threadIdx.x >> 4;

    __shared__ float t[64][68];

    #pragma unroll
    for (int cc = 0; cc < 64; cc += 16) {
        const int c = ty + cc;
        *(float4*)&t[c][tx * 4] = *(const float4*)&I[(size_t)(c0 + c) * NN + n0 + tx * 4];
    }
    __syncthreads();
    #pragma unroll
    for (int nn2 = 0; nn2 < 64; nn2 += 16) {
        const int n = n0 + ty + nn2;
        const int c = c0 + tx * 4;
        ushort4 p;
        p.x = f2bf(t[tx * 4 + 0][ty + nn2]);
        p.y = f2bf(t[tx * 4 + 1][ty + nn2]);
        p.z = f2bf(t[tx * 4 + 2][ty + nn2]);
        p.w = f2bf(t[tx * 4 + 3][ty + nn2]);
        *(ushort4*)&O[til(n, c, 8)] = p;
    }
}

// ---------------------------------------------------------------------------
// Q/K/V conv via MFMA, table-driven, all operands tiled, NOW with an
// async-staged pipeline: per-wave private 16-slot LDS ring (2 kc groups of
// 8 tiles: 4 A + 4 B), global_load_lds staging, counted vmcnt(8) waits,
// 2-kc lookahead, no in-loop barriers (slots are wave-private).
// isv=0: A=W(c rows), B=Xt(n rows); out tiled(n16,c32)   [Q/K]
// isv=1: A=Xt(n rows), B=W(c rows); out tiled(c16,n32)+bias [V]
// ---------------------------------------------------------------------------
struct QkvP {
    const u16* w[12]; const u16* x[12]; u16* out[12];
    const float* bias[12]; int isv[12];
};

__global__ __launch_bounds__(256) void conv_qkv(QkvP P)
{
    const int z = blockIdx.z, job = z >> 3, b = z & 7;
    const int isv = P.isv[job];
    const u16* Wp = P.w[job];
    const u16* Xp = P.x[job] + (size_t)b * (3 * NC);
    const int n0 = blockIdx.x * 128, c0 = blockIdx.y * 128;
    const int lane = threadIdx.x & 63, wave = threadIdx.x >> 6;
    const int l15 = lane & 15, lg = lane >> 4;
    const int rA = (wave >> 1) * 64, rB = (wave & 1) * 64;

    const u16* Ab = isv ? Xp : Wp;
    const u16* Bb = isv ? Wp : Xp;
    const int Ar0 = (isv ? n0 : c0) + rA;    // multiple of 16
    const int Br0 = (isv ? c0 : n0) + rB;

    __shared__ u16 ring[4][16][512];         // 4 waves x 16 slots x 1KB = 64KB
    u16* rw = &ring[wave][0][0];

    auto stage8 = [&](int kc, int grp) {
        #pragma unroll
        for (int i = 0; i < 4; i++)
            stage_tile(Ab + ((size_t)((Ar0 >> 4) + i) * 8 + kc) * 512,
                       rw + (size_t)(grp + i) * 512, lane);
        #pragma unroll
        for (int i = 0; i < 4; i++)
            stage_tile(Bb + ((size_t)((Br0 >> 4) + i) * 8 + kc) * 512,
                       rw + (size_t)(grp + 4 + i) * 512, lane);
    };

    // prologue: kc0 -> slots 0..7, kc1 -> slots 8..15 (16 in flight)
    stage8(0, 0);
    stage8(1, 8);

    const int roff = lg * 128 + l15 * 8;     // transposed-tile frag offset
    f32x4 acc[4][4] = {};

    #pragma unroll
    for (int kc = 0; kc < 8; kc++) {
        if (kc < 7) { WAITV(8); } else { WAITV(0); }   // this kc's 8 tiles landed
        const int g = (kc & 1) * 8;
        short8 av[4], bv[4];
        #pragma unroll
        for (int i = 0; i < 4; i++) av[i] = *(const short8*)&rw[(size_t)(g + i) * 512 + roff];
        #pragma unroll
        for (int i = 0; i < 4; i++) bv[i] = *(const short8*)&rw[(size_t)(g + 4 + i) * 512 + roff];
        asm volatile("s_waitcnt lgkmcnt(0)" ::: "memory");   // reads done before slot reuse
        __builtin_amdgcn_sched_barrier(0);
        if (kc + 2 < 8) stage8(kc + 2, g);                   // refill this group
        __builtin_amdgcn_s_setprio(1);
        #pragma unroll
        for (int i = 0; i < 4; i++)
            #pragma unroll
            for (int j = 0; j < 4; j++)
                acc[i][j] = __builtin_amdgcn_mfma_f32_16x16x32_bf16(av[i], bv[j], acc[i][j], 0, 0, 0);
        __builtin_amdgcn_s_setprio(0);
    }

    if (!isv) {
        u16* Ot = P.out[job] + (size_t)b * NC;
        #pragma unroll
        for (int i = 0; i < 4; i++) {
            const int c = c0 + rA + i * 16 + lg * 4;    // reg-packed dim
            #pragma unroll
            for (int j = 0; j < 4; j++) {
                const int n = n0 + rB + j * 16 + l15;
                ushort4 p;
                p.x = f2bf(acc[i][j][0]); p.y = f2bf(acc[i][j][1]);
                p.z = f2bf(acc[i][j][2]); p.w = f2bf(acc[i][j][3]);
                *(ushort4*)&Ot[til(n, c, 8)] = p;
            }
        }
    } else {
        u16* Ov = P.out[job] + (size_t)b * CN;
        const float* bias = P.bias[job];
        #pragma unroll
        for (int j = 0; j < 4; j++) {
            const int c = c0 + rB + j * 16 + l15;
            const float bi = bias[c];
            #pragma unroll
            for (int i = 0; i < 4; i++) {
                const int n = n0 + rA + i * 16 + lg * 4;  // reg-packed dim
                ushort4 p;
                p.x = f2bf(acc[i][j][0] + bi); p.y = f2bf(acc[i][j][1] + bi);
                p.z = f2bf(acc[i][j][2] + bi); p.w = f2bf(acc[i][j][3] + bi);
                *(ushort4*)&Ov[til(c, n, 64)] = p;
            }
        }
    }
}

// ---------------------------------------------------------------------------
// T-stage conv, bf16 in/out (round-7 proven)
// ---------------------------------------------------------------------------
__global__ __launch_bounds__(256) void conv_t2(
    const u16* __restrict__ W, const u16* __restrict__ Dt,
    const float* __restrict__ bias, const u16* __restrict__ Xts,
    u16* __restrict__ O)
{
    const int bid = blockIdx.x;
    const int b = bid & 7;
    const int rest = bid >> 3;           // 0..31
    const int cy = rest & 1, nx = rest >> 1;
    const int n0 = nx * 128, c0 = cy * 128;
    const int lane = threadIdx.x & 63, wave = threadIdx.x >> 6;
    const int l15 = lane & 15, lg = lane >> 4;
    const int wc = (wave >> 1) * 64, wn = (wave & 1) * 64;

    const u16* Xp = Dt + (size_t)b * NC;
    const u16* ap[4]; const u16* bp[4];
    #pragma unroll
    for (int i = 0; i < 4; i++) {
        ap[i] = W  + til(c0 + wc + i * 16 + l15, lg * 8, 8);
        bp[i] = Xp + til(n0 + wn + i * 16 + l15, lg * 8, 8);
    }

    f32x4 acc[4][4] = {};
    #pragma unroll 2
    for (int kc = 0; kc < 8; kc++) {
        short8 av[4], bv[4];
        #pragma unroll
        for (int i = 0; i < 4; i++) av[i] = *(const short8*)(ap[i] + kc * 512);
        #pragma unroll
        for (int i = 0; i < 4; i++) bv[i] = *(const short8*)(bp[i] + kc * 512);
        #pragma unroll
        for (int i = 0; i < 4; i++)
            #pragma unroll
            for (int j = 0; j < 4; j++)
                acc[i][j] = __builtin_amdgcn_mfma_f32_16x16x32_bf16(av[i], bv[j], acc[i][j], 0, 0, 0);
    }

    const u16* Xtb = Xts + (size_t)b * (3 * NC);
    u16* Ob = O + (size_t)b * CN;
    #pragma unroll
    for (int i = 0; i < 4; i++) {
        const int cb = c0 + wc + i * 16 + lg * 4;
        #pragma unroll
        for (int j = 0; j < 4; j++) {
            const int n = n0 + wn + j * 16 + l15;
            const ushort4 xv = *(const ushort4*)&Xtb[til(n, cb, 8)];
            const u16 xa[4] = { xv.x, xv.y, xv.z, xv.w };
            #pragma unroll
            for (int r = 0; r < 4; r++) {
                const int c = cb + r;
                const float v = bf2f(xa[r]) + fmaxf(acc[i][j][r] + bias[c], 0.0f);
                Ob[til(c, n, 64)] = f2bf(v);
            }
        }
    }
}

// ---------------------------------------------------------------------------
// attention (round-8 proven): async-staged K pipeline, 32 q-rows/block,
// 1024 thr (16 waves), 512 blocks, batch = bid&7 (XCD-pinned).
// S written blocked [b][n>>3][m][n&7]; per-block col partials.
// ---------------------------------------------------------------------------
__global__ __launch_bounds__(1024) void attn_mfma6(
    const u16* __restrict__ Q, const u16* __restrict__ K,
    u16* __restrict__ Sout, float* __restrict__ CPb)
{
    const int bid = blockIdx.x;
    const int b = bid & 7;
    const int nblk = bid >> 3;           // 0..63
    const int n0 = nblk * 32;
    const int tid = threadIdx.x, lane = tid & 63, wave = tid >> 6;
    const int l15 = lane & 15, lg = lane >> 4;

    const u16* Qt = Q + (size_t)b * NC;
    const u16* Kt = K + (size_t)b * NC;

    __shared__ u16 KL[16 * 8 * 512];     // 16 waves x 8 slots x 1KB = 128 KiB
    __shared__ u16 QL[16 * 512];         // 16 Q tiles
    __shared__ float red[16][32];
    __shared__ float rowstat[32];

    stage_tile(Qt + ((size_t)((n0 >> 4) + (wave >> 3)) * 8 + (wave & 7)) * 512,
               &QL[wave * 512], lane);
    u16* kw = &KL[wave * 4096];
    #pragma unroll
    for (int p = 0; p < 6; p++)
        stage_tile(Kt + ((size_t)(wave * 8 + (p & 7)) * 8 + (p >> 3)) * 512,
                   &kw[p * 512], lane);
    __syncthreads();

    f32x4 acc[2][8];
    #pragma unroll
    for (int g = 0; g < 2; g++)
        #pragma unroll
        for (int t = 0; t < 8; t++) acc[g][t] = (f32x4){0.f, 0.f, 0.f, 0.f};

    const int roff = lg * 128 + l15 * 8;

    #pragma unroll
    for (int kc = 0; kc < 8; kc++) {
        const short8 a0 = *(const short8*)&QL[kc * 512 + roff];
        const short8 a1 = *(const short8*)&QL[(8 + kc) * 512 + roff];
        #pragma unroll
        for (int t = 0; t < 8; t++) {
            const int i = kc * 8 + t;
            if (i < 58) { WAITV(5); } else if (i == 58) { WAITV(0); }
            const short8 bf = *(const short8*)&kw[(i & 7) * 512 + roff];
            if (i + 6 < 64) {
                const int j = i + 6;
                stage_tile(Kt + ((size_t)(wave * 8 + (j & 7)) * 8 + (j >> 3)) * 512,
                           &kw[(j & 7) * 512], lane);
            }
            __builtin_amdgcn_s_setprio(1);
            acc[0][t] = __builtin_amdgcn_mfma_f32_16x16x32_bf16(a0, bf, acc[0][t], 0, 0, 0);
            acc[1][t] = __builtin_amdgcn_mfma_f32_16x16x32_bf16(a1, bf, acc[1][t], 0, 0, 0);
            __builtin_amdgcn_s_setprio(0);
        }
    }

    // ---- row max ----
    float pm[2][4];
    #pragma unroll
    for (int g = 0; g < 2; g++)
        #pragma unroll
        for (int r = 0; r < 4; r++) {
            float m = acc[g][0][r];
            #pragma unroll
            for (int t = 1; t < 8; t++) m = fmaxf(m, acc[g][t][r]);
            #pragma unroll
            for (int o = 1; o <= 8; o <<= 1) m = fmaxf(m, __shfl_xor(m, o));
            pm[g][r] = m;
        }
    if (l15 == 0) {
        #pragma unroll
        for (int g = 0; g < 2; g++)
            #pragma unroll
            for (int r = 0; r < 4; r++) red[wave][g * 16 + lg * 4 + r] = pm[g][r];
    }
    __syncthreads();
    if (tid < 32) {
        float m = red[0][tid];
        #pragma unroll
        for (int w = 1; w < 16; w++) m = fmaxf(m, red[w][tid]);
        rowstat[tid] = m;
    }
    __syncthreads();

    float rm[2][4], ps[2][4];
    #pragma unroll
    for (int g = 0; g < 2; g++)
        #pragma unroll
        for (int r = 0; r < 4; r++) { rm[g][r] = rowstat[g * 16 + lg * 4 + r]; ps[g][r] = 0.f; }
    __syncthreads();

    // ---- exp in place + row-sum ----
    #pragma unroll
    for (int g = 0; g < 2; g++)
        #pragma unroll
        for (int t = 0; t < 8; t++)
            #pragma unroll
            for (int r = 0; r < 4; r++) {
                const float e = __expf(acc[g][t][r] - rm[g][r]);
                acc[g][t][r] = e; ps[g][r] += e;
            }
    #pragma unroll
    for (int g = 0; g < 2; g++)
        #pragma unroll
        for (int r = 0; r < 4; r++)
            #pragma unroll
            for (int o = 1; o <= 8; o <<= 1) ps[g][r] += __shfl_xor(ps[g][r], o);
    if (l15 == 0) {
        #pragma unroll
        for (int g = 0; g < 2; g++)
            #pragma unroll
            for (int r = 0; r < 4; r++) red[wave][g * 16 + lg * 4 + r] = ps[g][r];
    }
    __syncthreads();
    if (tid < 32) {
        float s = red[0][tid];
        #pragma unroll
        for (int w = 1; w < 16; w++) s += red[w][tid];
        rowstat[tid] = 1.0f / s;
    }
    __syncthreads();

    float rv[2][4];
    #pragma unroll
    for (int g = 0; g < 2; g++)
        #pragma unroll
        for (int r = 0; r < 4; r++) rv[g][r] = rowstat[g * 16 + lg * 4 + r];

    // ---- store S (blocked) + column partials ----
    u16* sb = Sout + (size_t)b * NN * NN;
    u16* sbg[2];
    #pragma unroll
    for (int g = 0; g < 2; g++)
        sbg[g] = sb + (size_t)((n0 >> 3) + g * 2 + (lg >> 1)) * (NN * 8) + (lg & 1) * 4;
    float* cpb = CPb + ((size_t)b * 64 + nblk) * NN;

    #pragma unroll
    for (int t = 0; t < 8; t++) {
        const int m = wave * 128 + t * 16 + l15;
        float cs = 0.0f;
        #pragma unroll
        for (int g = 0; g < 2; g++) {
            const float v0 = acc[g][t][0] * rv[g][0], v1 = acc[g][t][1] * rv[g][1];
            const float v2 = acc[g][t][2] * rv[g][2], v3 = acc[g][t][3] * rv[g][3];
            ushort4 pk;
            pk.x = f2bf(v0); pk.y = f2bf(v1); pk.z = f2bf(v2); pk.w = f2bf(v3);
            *(ushort4*)&sbg[g][(size_t)m * 8] = pk;
            cs += v0 + v1 + v2 + v3;
        }
        cs += __shfl_xor(cs, 16);
        cs += __shfl_xor(cs, 32);
        if (lane < 16) cpb[m] = cs;
    }
}

// ---------------------------------------------------------------------------
// colsum[b][m] = sum_{g<64} cspart[b][g][m]   (round-5 proven)
// ---------------------------------------------------------------------------
__global__ __launch_bounds__(256) void csum_kernel(const float* __restrict__ cp,
                                                   float* __restrict__ cs)
{
    const int b  = blockIdx.y;
    const int ml = threadIdx.x & 63;
    const int m  = blockIdx.x * 64 + ml;
    const int g0 = threadIdx.x >> 6;
    float s = 0.0f;
    for (int g = g0; g < 64; g += 4)
        s += cp[((size_t)b * 64 + g) * NN + m];
    __shared__ float red[4][64];
    red[g0][ml] = s;
    __syncthreads();
    if (threadIdx.x < 64) {
        cs[(size_t)b * NN + blockIdx.x * 64 + threadIdx.x] =
            red[0][threadIdx.x] + red[1][threadIdx.x] +
            red[2][threadIdx.x] + red[3][threadIdx.x];
    }
}

// ---------------------------------------------------------------------------
// pv + fused Dt (round-5 proven): Dt tiled(m16,c32) = bf16(Xt - PV/colsum)
// ---------------------------------------------------------------------------
__global__ __launch_bounds__(256) void pv_mfma(
    const u16* __restrict__ V, const u16* __restrict__ S,
    const float* __restrict__ CSb, const u16* __restrict__ Xts,
    u16* __restrict__ DTo)
{
    const int bid = blockIdx.x;
    const int b = bid & 7;
    const int r2 = bid >> 3;             // 0..63
    const int cy = r2 & 1, mx = r2 >> 1;
    const int m0b = mx * 64, c0 = cy * 128;
    const int lane = threadIdx.x & 63, wave = threadIdx.x >> 6;
    const int wc = (wave >> 1) * 64, wm = (wave & 1) * 32;
    const int l15 = lane & 15, lg = lane >> 4;

    const u16* Vm = V + (size_t)b * CN;
    const u16* Sm = S + (size_t)b * NN * NN;

    f32x4 acc[4][2] = {};
    const u16* vp[4]; const u16* sp[2];
    #pragma unroll
    for (int ai = 0; ai < 4; ai++)
        vp[ai] = Vm + til(c0 + wc + ai * 16 + l15, lg * 8, 64);
    #pragma unroll
    for (int bj = 0; bj < 2; bj++)
        sp[bj] = Sm + ((size_t)lg * NN + m0b + wm + bj * 16 + l15) * 8;

    #pragma unroll 2
    for (int kc = 0; kc < 64; kc++) {
        short8 a[4], s2[2];
        #pragma unroll
        for (int ai = 0; ai < 4; ai++) { a[ai] = *(const short8*)vp[ai]; vp[ai] += 512; }
        #pragma unroll
        for (int bj = 0; bj < 2; bj++) { s2[bj] = *(const short8*)sp[bj]; sp[bj] += (size_t)4 * NN * 8; }
        #pragma unroll
        for (int ai = 0; ai < 4; ai++)
            #pragma unroll
            for (int bj = 0; bj < 2; bj++)
                acc[ai][bj] = __builtin_amdgcn_mfma_f32_16x16x32_bf16(a[ai], s2[bj], acc[ai][bj], 0, 0, 0);
    }

    const u16* Xtb = Xts + (size_t)b * (3 * NC);
    u16* Dtb = DTo + (size_t)b * NC;

    #pragma unroll
    for (int bj = 0; bj < 2; bj++) {
        const int m = m0b + wm + bj * 16 + l15;
        const float inv = 1.0f / (1e-7f + CSb[(size_t)b * NN + m]);
        #pragma unroll
        for (int ai = 0; ai < 4; ai++) {
            const int c = c0 + wc + ai * 16 + lg * 4;   // reg-packed dim
            const size_t ad = til(m, c, 8);
            const ushort4 xv = *(const ushort4*)&Xtb[ad];
            ushort4 pk;
            pk.x = f2bf(bf2f(xv.x) - acc[ai][bj][0] * inv);
            pk.y = f2bf(bf2f(xv.y) - acc[ai][bj][1] * inv);
            pk.z = f2bf(bf2f(xv.z) - acc[ai][bj][2] * inv);
            pk.w = f2bf(bf2f(xv.w) - acc[ai][bj][3] * inv);
            *(ushort4*)&Dtb[ad] = pk;
        }
    }
}

// ---------------------------------------------------------------------------
// elementwise combines on bf16 tiled slabs (round-7 proven)
// ---------------------------------------------------------------------------
__global__ __launch_bounds__(256) void ew_update_t(u16* __restrict__ A,
                                                   const u16* __restrict__ Bv)
{
    const size_t e = ((size_t)blockIdx.x * 256 + threadIdx.x) * 8;
    short8 a = *(const short8*)&A[e];
    const short8 b = *(const short8*)&Bv[e];
    #pragma unroll
    for (int j = 0; j < 8; j++) {
        const float f = tanhf(bf2f((u16)a[j]) * sigf(bf2f((u16)b[j])));
        a[j] = (short)f2bf(f);
    }
    *(short8*)&A[e] = a;
}

__global__ __launch_bounds__(256) void ew_final_t(
    const u16* __restrict__ TU, const u16* __restrict__ SU,
    const u16* __restrict__ G, const float* __restrict__ x,
    float* __restrict__ OUT)
{
    const size_t e = ((size_t)blockIdx.x * 256 + threadIdx.x) * 8;
    const int b = (int)(e / CN);
    const size_t r = e - (size_t)b * CN;
    const int tile = (int)(r >> 9), win = (int)(r & 511);
    const int row = win >> 5, col = win & 31;
    const int c = (tile >> 6) * 16 + row;      // tiled(c16,n32), tpr=64
    const int n = (tile & 63) * 32 + col;

    const size_t lin = ((size_t)b * 3 + 1) * CN + (size_t)c * NN + n;  // mid slice
    const float4 m0 = *(const float4*)&x[lin];
    const float4 m1 = *(const float4*)&x[lin + 4];
    const float mid[8] = { m0.x, m0.y, m0.z, m0.w, m1.x, m1.y, m1.z, m1.w };

    const short8 tu = *(const short8*)&TU[e];
    const short8 su = *(const short8*)&SU[e];
    const short8 g  = *(const short8*)&G[e];

    float o[8];
    #pragma unroll
    for (int j = 0; j < 8; j++) {
        const float gg = bf2f((u16)g[j]);
        o[j] = mid[j] + sigf((bf2f((u16)tu[j]) + bf2f((u16)su[j])) * sigf(gg)) * tanhf(gg);
    }
    float* op = OUT + (size_t)b * CN + (size_t)c * NN + n;
    *(float4*)op       = (float4){o[0], o[1], o[2], o[3]};
    *(float4*)(op + 4) = (float4){o[4], o[5], o[6], o[7]};
}

// ---------------------------------------------------------------------------
extern "C" void kernel_launch(void* const* d_in, const int* in_sizes, int n_in,
                              void* d_out, int out_size, void* d_ws, size_t ws_size,
                              hipStream_t stream)
{
    const float* x   = (const float*)d_in[0];
    const float* Wqk = (const float*)d_in[1];
    const float* Vw  = (const float*)d_in[2];
    const float* VbF = (const float*)d_in[3];
    const float* Tw  = (const float*)d_in[4];
    const float* TbF = (const float*)d_in[5];
    float* out = (float*)d_out;

    // module meta: x-side slice (K,V) and y-side slice (Q). time=0 mid=1 space=2
    const int mxs[5] = {0, 2, 0, 2, 1};
    const int mys[5] = {0, 2, 2, 0, 1};
    const int qjob[5] = {0, 1, 5, 6, 4};
    const int q_wi[7] = {0, 1, 2, 3, 4, 2, 3};
    const int q_xi[7] = {0, 2, 0, 2, 1, 2, 0};

    const size_t WSZ     = (size_t)CC * CC;
    const size_t QK_SLAB = (size_t)BB * NC;              // elems (bf16)
    const size_t S_SLAB  = (size_t)BB * NN * NN;         // elems (bf16)
    const size_t CP_SLAB = (size_t)BB * 64 * NN;         // elems (f32)
    const size_t CS_SLAB = (size_t)BB * NN;              // elems (f32)
    const size_t O_SLAB  = (size_t)BB * CN;              // elems (bf16)

    const size_t base_b = 15 * WSZ * 2 + (size_t)BB * 3 * NC * 2;
    const size_t modtl  = S_SLAB * 2 + CP_SLAB * 4 + CS_SLAB * 4 + QK_SLAB * 2;
    const size_t margin = 2u << 20;
    const size_t need_1 = base_b + 12 * QK_SLAB * 2 + modtl + 3 * O_SLAB * 2 + margin;
    const size_t need_2 = base_b +  3 * QK_SLAB * 2 + modtl + 3 * O_SLAB * 2 + margin;

    const int tier2 = (ws_size >= need_1) ? 0 : 1;
    if (tier2 && ws_size < need_2) return;   // can't run: leave poison

    const int nQK = tier2 ? 2 : 7;
    const int nV  = tier2 ? 1 : 5;

    char* ws = (char*)d_ws;
    size_t off = 0;
    auto alloc = [&](size_t bytes) -> char* {
        char* p = ws + off; off += (bytes + 255) & ~255ULL; return p;
    };

    u16*   W16 = (u16*)  alloc(15 * WSZ * 2);
    u16*   Xt  = (u16*)  alloc((size_t)BB * 3 * NC * 2);
    u16*   QK  = (u16*)  alloc((size_t)nQK * QK_SLAB * 2);
    u16*   VB  = (u16*)  alloc((size_t)nV * QK_SLAB * 2);
    u16*   S   = (u16*)  alloc(S_SLAB * 2);
    float* CP  = (float*)alloc(CP_SLAB * 4);
    float* CS  = (float*)alloc(CS_SLAB * 4);
    u16*   DT  = (u16*)  alloc(QK_SLAB * 2);
    u16*   OB  = (u16*)  alloc(3 * O_SLAB * 2);

    cast_w<<<dim3(64, 5), 256, 0, stream>>>(Wqk, W16);
    cast_w<<<dim3(64, 5), 256, 0, stream>>>(Vw,  W16 + 5 * WSZ);
    cast_w<<<dim3(64, 5), 256, 0, stream>>>(Tw,  W16 + 10 * WSZ);
    tcast_x<<<dim3(NN / 64, CC / 64, BB * 3), 256, 0, stream>>>(x, Xt);

    if (!tier2) {
        QkvP qp{};
        for (int j = 0; j < 7; j++) {
            qp.w[j] = W16 + (size_t)q_wi[j] * WSZ;
            qp.x[j] = Xt + (size_t)q_xi[j] * NC;
            qp.out[j] = QK + (size_t)j * QK_SLAB;
            qp.isv[j] = 0; qp.bias[j] = nullptr;
        }
        for (int i = 0; i < 5; i++) {
            const int j = 7 + i;
            qp.w[j] = W16 + (size_t)(5 + i) * WSZ;
            qp.x[j] = Xt + (size_t)mxs[i] * NC;
            qp.out[j] = VB + (size_t)i * QK_SLAB;
            qp.isv[j] = 1; qp.bias[j] = VbF + (size_t)i * CC;
        }
        conv_qkv<<<dim3(NN / 128, CC / 128, 96), 256, 0, stream>>>(qp);
    }

    auto run_mod = [&](int i, u16* O) {
        const u16* Qp; const u16* Kp; const u16* Vp;
        if (!tier2) {
            Qp = QK + (size_t)qjob[i] * QK_SLAB;
            Kp = QK + (size_t)i * QK_SLAB;
            Vp = VB + (size_t)i * QK_SLAB;
        } else {
            QkvP qp{}; int nj = 0;
            qp.w[nj] = W16 + (size_t)i * WSZ; qp.x[nj] = Xt + (size_t)mxs[i] * NC;
            qp.out[nj] = QK; qp.isv[nj] = 0; nj++;
            Qp = QK; Kp = QK;
            if (mys[i] != mxs[i]) {
                qp.w[nj] = W16 + (size_t)i * WSZ; qp.x[nj] = Xt + (size_t)mys[i] * NC;
                qp.out[nj] = QK + QK_SLAB; qp.isv[nj] = 0; nj++;
                Qp = QK + QK_SLAB;
            }
            qp.w[nj] = W16 + (size_t)(5 + i) * WSZ; qp.x[nj] = Xt + (size_t)mxs[i] * NC;
            qp.out[nj] = VB; qp.isv[nj] = 1; qp.bias[nj] = VbF + (size_t)i * CC; nj++;
            conv_qkv<<<dim3(NN / 128, CC / 128, 8 * nj), 256, 0, stream>>>(qp);
            Vp = VB;
        }
        attn_mfma6<<<512, 1024, 0, stream>>>(Qp, Kp, S, CP);
        csum_kernel<<<dim3(NN / 64, BB), 256, 0, stream>>>(CP, CS);
        pv_mfma<<<512, 256, 0, stream>>>(Vp, S, CS, Xt + (size_t)mxs[i] * NC, DT);
        conv_t2<<<256, 256, 0, stream>>>(W16 + (size_t)(10 + i) * WSZ, DT,
                                         TbF + (size_t)i * CC,
                                         Xt + (size_t)mxs[i] * NC, O);
    };

    u16* OB0 = OB;
    u16* OB1 = OB + O_SLAB;
    u16* OB2 = OB + 2 * O_SLAB;
    const int ewg = (int)(((size_t)BB * CN) / (256 * 8));   // 2048 blocks

    run_mod(0, OB0);                                         // time_att
    run_mod(2, OB1);                                         // time_cor
    ew_update_t<<<ewg, 256, 0, stream>>>(OB0, OB1);          // OB0 = time_update
    run_mod(1, OB1);                                         // space_att
    run_mod(3, OB2);                                         // space_cor
    ew_update_t<<<ewg, 256, 0, stream>>>(OB1, OB2);          // OB1 = space_update
    run_mod(4, OB2);                                         // global_feat
    ew_final_t<<<ewg, 256, 0, stream>>>(OB0, OB1, OB2, x, out);
}